// Round 3
// baseline (546.906 us; speedup 1.0000x reference)
//
#include <hip/hip_runtime.h>
#include <hip/hip_bf16.h>

#define N_NODES 8192
#define E_EDGES 524288
#define D_DIM   256
#define NEG_FILL -1e9f

#define PROJ_BLOCKS 256
#define ROWS_PER_BLOCK 32
#define HIST_BLOCKS 64

typedef float vfloat4 __attribute__((ext_vector_type(4)));

__device__ __forceinline__ float bf2f(unsigned short u) {
    union { unsigned int i; float f; } v;
    v.i = ((unsigned int)u) << 16;
    return v.f;
}

// k0: zero the 8192-entry left-node histogram
__global__ void zero_kernel(int* __restrict__ hist) {
    hist[blockIdx.x * 256 + threadIdx.x] = 0;
}

// k1: blocks [0,256) compute A = h@W1[0:256], B = h@W1[256:512] -> bf16 ws;
//     blocks [256,320) histogram left-node counts.
__global__ void proj_hist_kernel(
    const float* __restrict__ h,
    const float* __restrict__ W1,
    const int* __restrict__ eidx,
    unsigned short* __restrict__ AB,
    int* __restrict__ hist)
{
    if (blockIdx.x < PROJ_BLOCKS) {
        __shared__ float hs[ROWS_PER_BLOCK * D_DIM];   // 32 KB
        const int t  = threadIdx.x;
        const int r0 = blockIdx.x * ROWS_PER_BLOCK;
        const float* hp = h + (long long)r0 * D_DIM;
        for (int i = t; i < ROWS_PER_BLOCK * D_DIM; i += 256) hs[i] = hp[i];
        __syncthreads();

        float accA[ROWS_PER_BLOCK];
        float accB[ROWS_PER_BLOCK];
        #pragma unroll
        for (int r = 0; r < ROWS_PER_BLOCK; ++r) { accA[r] = 0.f; accB[r] = 0.f; }

        for (int k = 0; k < D_DIM; k += 4) {
            float wa0 = W1[(k + 0) * D_DIM + t];
            float wa1 = W1[(k + 1) * D_DIM + t];
            float wa2 = W1[(k + 2) * D_DIM + t];
            float wa3 = W1[(k + 3) * D_DIM + t];
            float wb0 = W1[(256 + k + 0) * D_DIM + t];
            float wb1 = W1[(256 + k + 1) * D_DIM + t];
            float wb2 = W1[(256 + k + 2) * D_DIM + t];
            float wb3 = W1[(256 + k + 3) * D_DIM + t];
            #pragma unroll
            for (int r = 0; r < ROWS_PER_BLOCK; ++r) {
                const float4 hv = *(const float4*)&hs[r * D_DIM + k];
                accA[r] = fmaf(hv.x, wa0, accA[r]);
                accA[r] = fmaf(hv.y, wa1, accA[r]);
                accA[r] = fmaf(hv.z, wa2, accA[r]);
                accA[r] = fmaf(hv.w, wa3, accA[r]);
                accB[r] = fmaf(hv.x, wb0, accB[r]);
                accB[r] = fmaf(hv.y, wb1, accB[r]);
                accB[r] = fmaf(hv.z, wb2, accB[r]);
                accB[r] = fmaf(hv.w, wb3, accB[r]);
            }
        }

        unsigned short* A = AB;
        unsigned short* B = AB + (long long)N_NODES * D_DIM;
        #pragma unroll
        for (int r = 0; r < ROWS_PER_BLOCK; ++r) {
            union { float f; unsigned int i; } va, vb;
            va.f = accA[r]; vb.f = accB[r];
            unsigned int ra = (va.i + 0x7FFF + ((va.i >> 16) & 1)) >> 16;
            unsigned int rb = (vb.i + 0x7FFF + ((vb.i >> 16) & 1)) >> 16;
            A[(long long)(r0 + r) * D_DIM + t] = (unsigned short)ra;
            B[(long long)(r0 + r) * D_DIM + t] = (unsigned short)rb;
        }
    } else {
        const int tid = (blockIdx.x - PROJ_BLOCKS) * 256 + threadIdx.x;  // 16384 threads
        for (int e = tid; e < E_EDGES; e += HIST_BLOCKS * 256)
            atomicAdd(&hist[eidx[e]], 1);
    }
}

// k2: exclusive scan of 8192 counts -> rowStart[8193], cursor copy. One block.
__global__ void scan_kernel(const int* __restrict__ hist,
                            int* __restrict__ rowStart,
                            int* __restrict__ cursor)
{
    __shared__ int part[256];
    const int t = threadIdx.x;
    const int base = t * 32;
    int c[32];
    int s = 0;
    #pragma unroll
    for (int i = 0; i < 32; ++i) { c[i] = hist[base + i]; s += c[i]; }
    part[t] = s;
    __syncthreads();
    // Hillis-Steele inclusive scan over 256 partials
    for (int off = 1; off < 256; off <<= 1) {
        int v = (t >= off) ? part[t - off] : 0;
        __syncthreads();
        part[t] += v;
        __syncthreads();
    }
    int excl = part[t] - s;
    #pragma unroll
    for (int i = 0; i < 32; ++i) {
        rowStart[base + i] = excl;
        cursor[base + i]   = excl;
        excl += c[i];
    }
    if (t == 255) rowStart[N_NODES] = excl;   // = E
}

// k3: scatter edge ids into per-row buckets
__global__ void scatter_kernel(const int* __restrict__ eidx,
                               int* __restrict__ cursor,
                               int* __restrict__ bucket)
{
    const int tid = blockIdx.x * 256 + threadIdx.x;
    for (int e = tid; e < E_EDGES; e += 256 * 256) {
        int l = eidx[e];
        int pos = atomicAdd(&cursor[l], 1);
        bucket[pos] = e;
    }
}

// k4: one wave per output row: NT-fill the row with -1e9, drain, then compute
// scores for this row's edges (gather B only; A is held in registers).
__global__ __launch_bounds__(256) void rowwrite_kernel(
    const int* __restrict__ eidx,
    const float* __restrict__ eattr,
    const float* __restrict__ W1,
    const float* __restrict__ W2,
    const unsigned short* __restrict__ AB,
    const int* __restrict__ rowStart,
    const int* __restrict__ bucket,
    float* __restrict__ out)
{
    const int row  = (blockIdx.x << 2) + (threadIdx.x >> 6);   // 0..8191
    const int lane = threadIdx.x & 63;
    const int j0   = lane * 4;

    // A-row fragment (this wave's left node), per-lane constants
    const ushort4 a4 = *(const ushort4*)(AB + (long long)row * D_DIM + j0);
    const float af0 = bf2f(a4.x), af1 = bf2f(a4.y), af2 = bf2f(a4.z), af3 = bf2f(a4.w);
    const float4 wl = *(const float4*)&W1[512 * D_DIM + j0];
    const float4 w2 = *(const float4*)&W2[j0];

    // fill this row with -1e9 (nontemporal full-line stores)
    float* outrow = out + (long long)row * N_NODES;
    vfloat4 fv = { NEG_FILL, NEG_FILL, NEG_FILL, NEG_FILL };
    vfloat4* o4 = (vfloat4*)outrow;
    #pragma unroll
    for (int i = 0; i < 32; ++i)
        __builtin_nontemporal_store(fv, &o4[i * 64 + lane]);

    // drain stores so this wave's later score stores order after the fill
    __builtin_amdgcn_s_waitcnt(0);

    const unsigned short* B  = AB + (long long)N_NODES * D_DIM;
    const int* eR = eidx + E_EDGES;

    const int start = rowStart[row];
    const int end   = rowStart[row + 1];

    int   r_nxt  = 0;
    float at_nxt = 0.f;
    if (start < end) {
        int id = bucket[start];
        r_nxt  = eR[id];
        at_nxt = eattr[id];
    }
    for (int e = start; e < end; ++e) {
        const int   r    = r_nxt;
        const float attr = at_nxt;
        if (e + 1 < end) {                       // software prefetch of next edge
            int id = bucket[e + 1];
            r_nxt  = eR[id];
            at_nxt = eattr[id];
        }
        const ushort4 b4 = *(const ushort4*)(B + (long long)r * D_DIM + j0);
        float s = 0.f, hv;
        hv = fmaf(attr, wl.x, af0 + bf2f(b4.x)); hv = fmaxf(hv, 0.f); s = fmaf(hv, w2.x, s);
        hv = fmaf(attr, wl.y, af1 + bf2f(b4.y)); hv = fmaxf(hv, 0.f); s = fmaf(hv, w2.y, s);
        hv = fmaf(attr, wl.z, af2 + bf2f(b4.z)); hv = fmaxf(hv, 0.f); s = fmaf(hv, w2.z, s);
        hv = fmaf(attr, wl.w, af3 + bf2f(b4.w)); hv = fmaxf(hv, 0.f); s = fmaf(hv, w2.w, s);
        #pragma unroll
        for (int off = 32; off > 0; off >>= 1)
            s += __shfl_xor(s, off, 64);
        if (lane == 0)
            outrow[r] = s;
    }
}

extern "C" void kernel_launch(void* const* d_in, const int* in_sizes, int n_in,
                              void* d_out, int out_size, void* d_ws, size_t ws_size,
                              hipStream_t stream) {
    // inputs: 0=encoded (unused), 1=h, 2=edge_index, 3=edge_attr, 4=W1, 5=W2
    const float* h     = (const float*)d_in[1];
    const int*   eidx  = (const int*)d_in[2];
    const float* eattr = (const float*)d_in[3];
    const float* W1    = (const float*)d_in[4];
    const float* W2    = (const float*)d_in[5];
    float* out = (float*)d_out;

    char* ws = (char*)d_ws;
    unsigned short* AB   = (unsigned short*)(ws);                       // 8 MiB
    int* hist     = (int*)(ws + (8 << 20));                             // 32 KB
    int* cursor   = (int*)(ws + (8 << 20) + (32 << 10));                // 32 KB
    int* rowStart = (int*)(ws + (8 << 20) + (64 << 10));                // 32 KB + 4
    int* bucket   = (int*)(ws + (8 << 20) + (128 << 10));               // 2 MiB

    zero_kernel<<<N_NODES / 256, 256, 0, stream>>>(hist);
    proj_hist_kernel<<<PROJ_BLOCKS + HIST_BLOCKS, 256, 0, stream>>>(h, W1, eidx, AB, hist);
    scan_kernel<<<1, 256, 0, stream>>>(hist, rowStart, cursor);
    scatter_kernel<<<256, 256, 0, stream>>>(eidx, cursor, bucket);
    rowwrite_kernel<<<N_NODES / 4, 256, 0, stream>>>(eidx, eattr, W1, W2, AB,
                                                     rowStart, bucket, out);
}

// Round 4
// 519.159 us; speedup vs baseline: 1.0534x; 1.0534x over previous
//
#include <hip/hip_runtime.h>

#define N_NODES 8192
#define E_EDGES 524288
#define D_DIM   256
#define NEG_FILL -1e9f

#define PROJ_BLOCKS 256
#define ROWS_PER_BLOCK 32
#define FILL_BLOCKS 2048

typedef float vfloat4 __attribute__((ext_vector_type(4)));
typedef float vfloat2 __attribute__((ext_vector_type(2)));

// Fused kernel: blocks [0, PROJ_BLOCKS) compute A = h@W1[0:256], B = h@W1[256:512],
// stored as fp8 e4m3 into ws (4 MiB total -> fits each XCD's 4 MiB L2).
// Remaining blocks fill out with -1e9 (NT stores). Proj is VALU/LDS-bound and
// hides under the store-BW-bound fill.
__global__ __launch_bounds__(256) void fill_proj_kernel(
    const float* __restrict__ h,
    const float* __restrict__ W1,
    float* __restrict__ out,
    unsigned char* __restrict__ AB)   // A at [0, N*D), B at [N*D, 2*N*D)
{
    if (blockIdx.x < PROJ_BLOCKS) {
        __shared__ float hs[ROWS_PER_BLOCK * D_DIM];   // 32 KB
        const int t  = threadIdx.x;
        const int r0 = blockIdx.x * ROWS_PER_BLOCK;
        const float* hp = h + (long long)r0 * D_DIM;
        for (int i = t; i < ROWS_PER_BLOCK * D_DIM; i += 256) hs[i] = hp[i];
        __syncthreads();

        float accA[ROWS_PER_BLOCK];
        float accB[ROWS_PER_BLOCK];
        #pragma unroll
        for (int r = 0; r < ROWS_PER_BLOCK; ++r) { accA[r] = 0.f; accB[r] = 0.f; }

        for (int k = 0; k < D_DIM; k += 4) {
            float wa0 = W1[(k + 0) * D_DIM + t];
            float wa1 = W1[(k + 1) * D_DIM + t];
            float wa2 = W1[(k + 2) * D_DIM + t];
            float wa3 = W1[(k + 3) * D_DIM + t];
            float wb0 = W1[(256 + k + 0) * D_DIM + t];
            float wb1 = W1[(256 + k + 1) * D_DIM + t];
            float wb2 = W1[(256 + k + 2) * D_DIM + t];
            float wb3 = W1[(256 + k + 3) * D_DIM + t];
            #pragma unroll
            for (int r = 0; r < ROWS_PER_BLOCK; ++r) {
                const float4 hv = *(const float4*)&hs[r * D_DIM + k];
                accA[r] = fmaf(hv.x, wa0, accA[r]);
                accA[r] = fmaf(hv.y, wa1, accA[r]);
                accA[r] = fmaf(hv.z, wa2, accA[r]);
                accA[r] = fmaf(hv.w, wa3, accA[r]);
                accB[r] = fmaf(hv.x, wb0, accB[r]);
                accB[r] = fmaf(hv.y, wb1, accB[r]);
                accB[r] = fmaf(hv.z, wb2, accB[r]);
                accB[r] = fmaf(hv.w, wb3, accB[r]);
            }
        }

        unsigned char* A = AB;
        unsigned char* B = AB + (long long)N_NODES * D_DIM;
        #pragma unroll
        for (int r = 0; r < ROWS_PER_BLOCK; ++r) {
            // HW fp8 e4m3 (OCP) encode, RNE + saturate
            int pa = __builtin_amdgcn_cvt_pk_fp8_f32(accA[r], accA[r], 0, false);
            int pb = __builtin_amdgcn_cvt_pk_fp8_f32(accB[r], accB[r], 0, false);
            A[(long long)(r0 + r) * D_DIM + t] = (unsigned char)(pa & 0xFF);
            B[(long long)(r0 + r) * D_DIM + t] = (unsigned char)(pb & 0xFF);
        }
    } else {
        const int b  = blockIdx.x - PROJ_BLOCKS;
        const int nb = gridDim.x - PROJ_BLOCKS;
        const int nvec = (N_NODES / 4) * N_NODES;   // 16777216
        vfloat4 fv = { NEG_FILL, NEG_FILL, NEG_FILL, NEG_FILL };
        vfloat4* o4 = (vfloat4*)out;
        for (int i = b * 256 + threadIdx.x; i < nvec; i += nb * 256)
            __builtin_nontemporal_store(fv, &o4[i]);
    }
}

// One wave per edge: each lane handles 4 of the 256 hidden dims (fp8 gathers:
// 4 B/lane x 64 lanes = one 256 B row per table). Direct scatter of the score.
__global__ __launch_bounds__(256) void edge_kernel(
    const int* __restrict__ eidx,
    const float* __restrict__ eattr,
    const float* __restrict__ W1,
    const float* __restrict__ W2,
    const unsigned char* __restrict__ AB,
    float* __restrict__ out)
{
    const int wave = blockIdx.x * 4 + (threadIdx.x >> 6);
    const int lane = threadIdx.x & 63;

    const int   l    = eidx[wave];
    const int   r    = eidx[E_EDGES + wave];
    const float attr = eattr[wave];

    const int j0 = lane * 4;
    const unsigned int av = *(const unsigned int*)(AB + (long long)l * D_DIM + j0);
    const unsigned int bv = *(const unsigned int*)(AB + (long long)N_NODES * D_DIM
                                                      + (long long)r * D_DIM + j0);
    const float4 wl = *(const float4*)&W1[512 * D_DIM + j0];
    const float4 w2 = *(const float4*)&W2[j0];

    // HW fp8->f32 decode, 2 at a time
    vfloat2 a01 = __builtin_amdgcn_cvt_pk_f32_fp8((int)av, false);
    vfloat2 a23 = __builtin_amdgcn_cvt_pk_f32_fp8((int)av, true);
    vfloat2 b01 = __builtin_amdgcn_cvt_pk_f32_fp8((int)bv, false);
    vfloat2 b23 = __builtin_amdgcn_cvt_pk_f32_fp8((int)bv, true);

    float s = 0.f, hv;
    hv = fmaf(attr, wl.x, a01.x + b01.x); hv = fmaxf(hv, 0.f); s = fmaf(hv, w2.x, s);
    hv = fmaf(attr, wl.y, a01.y + b01.y); hv = fmaxf(hv, 0.f); s = fmaf(hv, w2.y, s);
    hv = fmaf(attr, wl.z, a23.x + b23.x); hv = fmaxf(hv, 0.f); s = fmaf(hv, w2.z, s);
    hv = fmaf(attr, wl.w, a23.y + b23.y); hv = fmaxf(hv, 0.f); s = fmaf(hv, w2.w, s);

    #pragma unroll
    for (int off = 32; off > 0; off >>= 1)
        s += __shfl_xor(s, off, 64);

    if (lane == 0)
        out[(long long)l * N_NODES + r] = s;
}

extern "C" void kernel_launch(void* const* d_in, const int* in_sizes, int n_in,
                              void* d_out, int out_size, void* d_ws, size_t ws_size,
                              hipStream_t stream) {
    // inputs: 0=encoded (unused), 1=h, 2=edge_index, 3=edge_attr, 4=W1, 5=W2
    const float* h     = (const float*)d_in[1];
    const int*   eidx  = (const int*)d_in[2];
    const float* eattr = (const float*)d_in[3];
    const float* W1    = (const float*)d_in[4];
    const float* W2    = (const float*)d_in[5];
    float* out = (float*)d_out;
    unsigned char* AB = (unsigned char*)d_ws;   // 4 MiB (2 * N * D fp8)

    fill_proj_kernel<<<PROJ_BLOCKS + FILL_BLOCKS, 256, 0, stream>>>(h, W1, out, AB);
    edge_kernel<<<E_EDGES / 4, 256, 0, stream>>>(eidx, eattr, W1, W2, AB, out);
}